// Round 2
// baseline (456.963 us; speedup 1.0000x reference)
//
#include <hip/hip_runtime.h>
#include <hip/hip_bf16.h>
#include <hip/hip_fp16.h>

// Problem constants (match reference)
#define NN 100000
#define EE 1600000
#define INF_DIM 128
#define NHEAD 4
#define HDIM 32
#define NEG_SLOPE 0.2f

typedef __attribute__((ext_vector_type(8))) short short8;
typedef __attribute__((ext_vector_type(4))) float floatx4;

__device__ __forceinline__ unsigned short f2bf(float x) {
  union { float f; unsigned int u; } c;
  c.f = x;
  const unsigned int r = c.u + 0x7fffu + ((c.u >> 16) & 1u);  // RNE
  return (unsigned short)(r >> 16);
}
// unpack packed pair of bf16 (from one u32) to two floats
__device__ __forceinline__ void bf2x(unsigned int u, float& lo, float& hi) {
  union { unsigned int u; float f; } a, b;
  a.u = u << 16;
  b.u = u & 0xffff0000u;
  lo = a.f;
  hi = b.f;
}
// fma 8 bf16 features (one uint4) into acc[8] with scalar weight c
__device__ __forceinline__ void accum8(const uint4 g, const float c,
                                       float* acc) {
  float lo, hi;
  bf2x(g.x, lo, hi);
  acc[0] = fmaf(c, lo, acc[0]);
  acc[1] = fmaf(c, hi, acc[1]);
  bf2x(g.y, lo, hi);
  acc[2] = fmaf(c, lo, acc[2]);
  acc[3] = fmaf(c, hi, acc[3]);
  bf2x(g.z, lo, hi);
  acc[4] = fmaf(c, lo, acc[4]);
  acc[5] = fmaf(c, hi, acc[5]);
  bf2x(g.w, lo, hi);
  acc[6] = fmaf(c, lo, acc[6]);
  acc[7] = fmaf(c, hi, acc[7]);
}

// ---------------------------------------------------------------------------
// MFMA GEMM: C[M,128] = A[M,128] @ W[128,128]^T (+bias), W row-major [o][k].
// A input: fp32 (Af) or bf16 (Ab). Output: bf16 (Cb) or fp32+bias (Cf).
// Block = 64 rows x 128 cols, 4 waves; K=128 staged once to LDS (bf16).
// ---------------------------------------------------------------------------
#define LDA 136

__global__ __launch_bounds__(256) void gemm_mfma(
    const float* __restrict__ Af, const unsigned short* __restrict__ Ab,
    const float* __restrict__ W, const float* __restrict__ bias,
    unsigned short* __restrict__ Cb, float* __restrict__ Cf, int M) {
  __shared__ unsigned short sA[64 * LDA];   // [m][k]
  __shared__ unsigned short sW[128 * LDA];  // [o][k] == B^T
  const int tid = threadIdx.x;
  const int m0 = blockIdx.x * 64;

  {
    const int r = tid >> 1;
    const int c0 = (tid & 1) * 64;
#pragma unroll
    for (int j = 0; j < 16; ++j) {
      const float4 v = *(const float4*)&W[r * 128 + c0 + j * 4];
      ushort4 u;
      u.x = f2bf(v.x);
      u.y = f2bf(v.y);
      u.z = f2bf(v.z);
      u.w = f2bf(v.w);
      *(ushort4*)&sW[r * LDA + c0 + j * 4] = u;
    }
  }
  {
    const int r = tid >> 2;
    const int gm = m0 + r;
    const int c0 = (tid & 3) * 32;
    if (gm < M) {
      if (Af) {
#pragma unroll
        for (int j = 0; j < 8; ++j) {
          const float4 v = *(const float4*)&Af[(size_t)gm * 128 + c0 + j * 4];
          ushort4 u;
          u.x = f2bf(v.x);
          u.y = f2bf(v.y);
          u.z = f2bf(v.z);
          u.w = f2bf(v.w);
          *(ushort4*)&sA[r * LDA + c0 + j * 4] = u;
        }
      } else {
#pragma unroll
        for (int j = 0; j < 4; ++j) {
          const uint4 v = *(const uint4*)&Ab[(size_t)gm * 128 + c0 + j * 8];
          *(uint4*)&sA[r * LDA + c0 + j * 8] = v;
        }
      }
    } else {
#pragma unroll
      for (int j = 0; j < 4; ++j) {
        uint4 z;
        z.x = z.y = z.z = z.w = 0u;
        *(uint4*)&sA[r * LDA + c0 + j * 8] = z;
      }
    }
  }
  __syncthreads();

  const int wv = tid >> 6;
  const int lane = tid & 63;
  const int l16 = lane & 15;
  const int quad = lane >> 4;

  floatx4 acc[8];
#pragma unroll
  for (int i = 0; i < 8; ++i) acc[i] = (floatx4){0.f, 0.f, 0.f, 0.f};

  const unsigned short* aRow = &sA[(wv * 16 + l16) * LDA + quad * 8];
#pragma unroll
  for (int kc = 0; kc < 4; ++kc) {
    const short8 afrag = *(const short8*)(aRow + kc * 32);
#pragma unroll
    for (int nt = 0; nt < 8; ++nt) {
      const short8 bfrag =
          *(const short8*)&sW[(nt * 16 + l16) * LDA + kc * 32 + quad * 8];
      acc[nt] =
          __builtin_amdgcn_mfma_f32_16x16x32_bf16(afrag, bfrag, acc[nt], 0, 0, 0);
    }
  }

  const int mrow = m0 + wv * 16 + quad * 4;
#pragma unroll
  for (int nt = 0; nt < 8; ++nt) {
    const int col = nt * 16 + l16;
    const float bv = Cf ? bias[col] : 0.f;
#pragma unroll
    for (int r = 0; r < 4; ++r) {
      const int gm = mrow + r;
      if (gm < M) {
        const float v = acc[nt][r];
        if (Cb)
          Cb[(size_t)gm * 128 + col] = f2bf(v);
        else
          Cf[(size_t)gm * 128 + col] = v + bv;
      }
    }
  }
}

// ---------------------------------------------------------------------------
// a_s[n,h] = dot(hb[n,h,:], att_src[h,:]); a_d likewise. One thread per (n,h).
// ---------------------------------------------------------------------------
__global__ void attn_dots(const unsigned short* __restrict__ hb,
                          const float* __restrict__ att_src,
                          const float* __restrict__ att_dst,
                          float* __restrict__ a_s, float* __restrict__ a_d) {
  const int idx = blockIdx.x * blockDim.x + threadIdx.x;  // n*4 + head
  if (idx >= NN * NHEAD) return;
  const int hd = idx & 3;
  const uint4* hp = (const uint4*)(hb + (size_t)idx * HDIM);
  const float4* as = (const float4*)(att_src + hd * HDIM);
  const float4* ad = (const float4*)(att_dst + hd * HDIM);
  float s = 0.f, d = 0.f;
#pragma unroll
  for (int q = 0; q < 4; ++q) {
    const uint4 u = hp[q];
    float v[8];
    bf2x(u.x, v[0], v[1]);
    bf2x(u.y, v[2], v[3]);
    bf2x(u.z, v[4], v[5]);
    bf2x(u.w, v[6], v[7]);
    const float4 a0 = as[q * 2], a1 = as[q * 2 + 1];
    const float4 b0 = ad[q * 2], b1 = ad[q * 2 + 1];
    s += v[0] * a0.x + v[1] * a0.y + v[2] * a0.z + v[3] * a0.w;
    s += v[4] * a1.x + v[5] * a1.y + v[6] * a1.z + v[7] * a1.w;
    d += v[0] * b0.x + v[1] * b0.y + v[2] * b0.z + v[3] * b0.w;
    d += v[4] * b1.x + v[5] * b1.y + v[6] * b1.z + v[7] * b1.w;
  }
  a_s[idx] = s;
  a_d[idx] = d;
}

// ---------------------------------------------------------------------------
// CSR build: histogram of dst, segment allocation via wave-scan + one atomic
// per wave, then scatter of ONLY the src index (4 B record). Per-edge softmax
// weights are recomputed in the aggregate kernel from the L2-resident a_s/a_d
// tables, eliminating ~140 MB of line-granular scattered record traffic.
// ---------------------------------------------------------------------------
__global__ void hist_kernel(const int* __restrict__ dst, int* __restrict__ deg) {
  const int i = blockIdx.x * blockDim.x + threadIdx.x;
  if (i < EE) atomicAdd(&deg[dst[i]], 1);
}

__global__ __launch_bounds__(256) void alloc_kernel(const int* __restrict__ deg,
                                                    int* __restrict__ rowptr,
                                                    int* __restrict__ cur,
                                                    int* __restrict__ counter) {
  const int i = blockIdx.x * blockDim.x + threadIdx.x;
  const int lane = threadIdx.x & 63;
  const int d = (i < NN) ? deg[i] : 0;
  int s = d;
#pragma unroll
  for (int off = 1; off < 64; off <<= 1) {
    const int v = __shfl_up(s, off, 64);
    if (lane >= off) s += v;
  }
  const int total = __shfl(s, 63, 64);
  int base = 0;
  if (lane == 63) base = atomicAdd(counter, total);
  base = __shfl(base, 63, 64);
  const int p = base + s - d;
  if (i < NN) {
    rowptr[i] = p;
    cur[i] = p;
  }
}

__global__ void scatter_kernel(const int* __restrict__ src,
                               const int* __restrict__ dst,
                               int* __restrict__ cur,
                               int* __restrict__ srcbuf) {
  const int i = blockIdx.x * blockDim.x + threadIdx.x;
  if (i >= EE) return;
  const int s = src[i];
  const int d = dst[i];
  const int p = atomicAdd(&cur[d], 1);
  srcbuf[p] = s;
}

// ---------------------------------------------------------------------------
// Aggregate v3: one wave per destination node, quarter-wave per edge.
// Lane layout: q = lane>>4 (edge slot), f = lane&15 (feature group).
// Lane owns features [8f, 8f+8) -> one uint4 (16 B) of the bf16 feature row;
// its head is f>>2 (head-aligned). Per loop iteration the wave processes 4
// edges: one dword src-index load (broadcast within quarter) + one uint4
// feature gather + one dword a_s gather (1.6 MB L2-resident table). The
// softmax weight c = exp(leakyrelu(a_s[s][h] + a_d[n][h])) is computed in
// fp32 in-loop (a_d term is loop-invariant). src indices software-pipelined.
// Per-head denominator + features reduce across quarters via shfl_xor(16/32).
// ---------------------------------------------------------------------------
__global__ __launch_bounds__(256) void aggregate_kernel(
    const uint4* __restrict__ hbd4, const float* __restrict__ a_s,
    const float* __restrict__ a_d, const float* __restrict__ bias_gat,
    const int* __restrict__ rowptr, const int* __restrict__ deg,
    const int* __restrict__ srcbuf, uint4* __restrict__ obd4) {
  const int wave = (blockIdx.x * blockDim.x + threadIdx.x) >> 6;
  if (wave >= NN) return;
  const int lane = threadIdx.x & 63;
  const int q = lane >> 4;
  const int f = lane & 15;
  const int head = f >> 2;
  const int n = wave;

  const float adv = a_d[n * 4 + head];  // loop-invariant dst term

  float acc[8];
  float ds;
  {  // self loop (only quarter 0 contributes; others start at zero)
    const float l0 = a_s[n * 4 + head] + adv;
    const float l = fmaxf(l0, NEG_SLOPE * l0);
    float cs = __expf(l);
    if (q != 0) cs = 0.f;
    const uint4 g = hbd4[(size_t)n * 16 + f];
    float lo, hi;
    bf2x(g.x, lo, hi);
    acc[0] = cs * lo;
    acc[1] = cs * hi;
    bf2x(g.y, lo, hi);
    acc[2] = cs * lo;
    acc[3] = cs * hi;
    bf2x(g.z, lo, hi);
    acc[4] = cs * lo;
    acc[5] = cs * hi;
    bf2x(g.w, lo, hi);
    acc[6] = cs * lo;
    acc[7] = cs * hi;
    ds = cs;
  }

  const int beg = rowptr[n];
  const int end = beg + deg[n];
  if (beg < end) {
    int idx = beg + q;
    bool valid = idx < end;
    int s = srcbuf[valid ? idx : end - 1];
    for (int i = beg; i < end; i += 4) {
      // gather this quarter's edge features (one uint4/lane) + a_s term
      const uint4 g = hbd4[(size_t)s * 16 + f];
      const float asv = a_s[s * 4 + head];
      // prefetch next src indices while the gathers are in flight
      const int nidx = i + 4 + q;
      const bool nvalid = nidx < end;
      const int sn = srcbuf[nvalid ? nidx : end - 1];
      // softmax weight (fp32, masked on tail slots)
      const float l0 = asv + adv;
      const float l = fmaxf(l0, NEG_SLOPE * l0);
      float c = __expf(l);
      if (!valid) c = 0.f;
      accum8(g, c, acc);
      ds += c;
      s = sn;
      valid = nvalid;
    }
  }

  // reduce across the 4 quarters (lanes l, l^16, l^32, l^48 share f)
#pragma unroll
  for (int j = 0; j < 8; ++j) {
    acc[j] += __shfl_xor(acc[j], 16);
    acc[j] += __shfl_xor(acc[j], 32);
  }
  ds += __shfl_xor(ds, 16);
  ds += __shfl_xor(ds, 32);

  if (q == 0) {
    const float inv = 1.0f / ds;
    const float4 b0 = *(const float4*)&bias_gat[f * 8];
    const float4 b1 = *(const float4*)&bias_gat[f * 8 + 4];
    float v0 = acc[0] * inv + b0.x;
    float v1 = acc[1] * inv + b0.y;
    float v2 = acc[2] * inv + b0.z;
    float v3 = acc[3] * inv + b0.w;
    float v4 = acc[4] * inv + b1.x;
    float v5 = acc[5] * inv + b1.y;
    float v6 = acc[6] * inv + b1.z;
    float v7 = acc[7] * inv + b1.w;
    v0 = v0 > 0.f ? v0 : 0.f;
    v1 = v1 > 0.f ? v1 : 0.f;
    v2 = v2 > 0.f ? v2 : 0.f;
    v3 = v3 > 0.f ? v3 : 0.f;
    v4 = v4 > 0.f ? v4 : 0.f;
    v5 = v5 > 0.f ? v5 : 0.f;
    v6 = v6 > 0.f ? v6 : 0.f;
    v7 = v7 > 0.f ? v7 : 0.f;
    uint4 r;
    r.x = (unsigned int)f2bf(v0) | ((unsigned int)f2bf(v1) << 16);
    r.y = (unsigned int)f2bf(v2) | ((unsigned int)f2bf(v3) << 16);
    r.z = (unsigned int)f2bf(v4) | ((unsigned int)f2bf(v5) << 16);
    r.w = (unsigned int)f2bf(v6) | ((unsigned int)f2bf(v7) << 16);
    obd4[(size_t)n * 16 + f] = r;
  }
}

// ---------------------------------------------------------------------------
extern "C" void kernel_launch(void* const* d_in, const int* in_sizes, int n_in,
                              void* d_out, int out_size, void* d_ws,
                              size_t ws_size, hipStream_t stream) {
  const float* x = (const float*)d_in[0];
  const int* ei = (const int*)d_in[1];  // [2,E]: row0=src, row1=dst
  const float* W_gat = (const float*)d_in[2];
  const float* att_src = (const float*)d_in[3];
  const float* att_dst = (const float*)d_in[4];
  const float* bias_gat = (const float*)d_in[5];
  const float* W_lin = (const float*)d_in[6];
  const float* b_lin = (const float*)d_in[7];
  float* out = (float*)d_out;

  // workspace carve-up (16B aligned)
  char* ws = (char*)d_ws;
  size_t off = 0;
  unsigned short* hb = (unsigned short*)(ws + off);
  off += (size_t)NN * 128 * 2;  // 25.6 MB
  unsigned short* ob = (unsigned short*)(ws + off);
  off += (size_t)NN * 128 * 2;  // 25.6 MB
  float* a_s = (float*)(ws + off); off += (size_t)NN * 4 * 4;
  float* a_d = (float*)(ws + off); off += (size_t)NN * 4 * 4;
  int* deg = (int*)(ws + off); off += (size_t)NN * 4;
  int* rowptr = (int*)(ws + off); off += (size_t)(NN + 4) * 4;
  int* cur = (int*)(ws + off); off += (size_t)NN * 4;
  int* counter = (int*)(ws + off); off += 16;
  int* srcbuf = (int*)(ws + off); off += (size_t)EE * 4;  // 6.4 MB

  const int* src = ei;
  const int* dst = ei + EE;

  // 1) hb = bf16(x @ W_gat^T)  [MFMA]
  gemm_mfma<<<(NN + 63) / 64, 256, 0, stream>>>(x, nullptr, W_gat, nullptr, hb,
                                                nullptr, NN);
  // 2) attention dots from bf16 features
  attn_dots<<<(NN * NHEAD + 255) / 256, 256, 0, stream>>>(hb, att_src, att_dst,
                                                          a_s, a_d);
  // 3) CSR by destination (src-index-only records)
  hipMemsetAsync(deg, 0, (size_t)NN * 4, stream);
  hipMemsetAsync(counter, 0, 16, stream);
  hist_kernel<<<(EE + 255) / 256, 256, 0, stream>>>(dst, deg);
  alloc_kernel<<<(NN + 255) / 256, 256, 0, stream>>>(deg, rowptr, cur, counter);
  scatter_kernel<<<(EE + 255) / 256, 256, 0, stream>>>(src, dst, cur, srcbuf);
  // 4) softmax-weighted aggregation (+bias, relu) -> bf16
  aggregate_kernel<<<(NN + 3) / 4, 256, 0, stream>>>(
      (const uint4*)hb, a_s, a_d, bias_gat, rowptr, deg, srcbuf,
      (uint4*)ob);
  // 5) out = ob @ W_lin^T + b_lin  [MFMA]
  gemm_mfma<<<(NN + 63) / 64, 256, 0, stream>>>(nullptr, ob, W_lin, b_lin,
                                                nullptr, out, NN);
}

// Round 3
// 412.912 us; speedup vs baseline: 1.1067x; 1.1067x over previous
//
#include <hip/hip_runtime.h>
#include <hip/hip_bf16.h>
#include <hip/hip_fp16.h>

// Problem constants (match reference)
#define NN 100000
#define EE 1600000
#define INF_DIM 128
#define NHEAD 4
#define HDIM 32
#define NEG_SLOPE 0.2f

typedef __attribute__((ext_vector_type(8))) short short8;
typedef __attribute__((ext_vector_type(4))) float floatx4;

__device__ __forceinline__ unsigned short f2bf(float x) {
  union { float f; unsigned int u; } c;
  c.f = x;
  const unsigned int r = c.u + 0x7fffu + ((c.u >> 16) & 1u);  // RNE
  return (unsigned short)(r >> 16);
}
// unpack packed pair of bf16 (from one u32) to two floats
__device__ __forceinline__ void bf2x(unsigned int u, float& lo, float& hi) {
  union { unsigned int u; float f; } a, b;
  a.u = u << 16;
  b.u = u & 0xffff0000u;
  lo = a.f;
  hi = b.f;
}
__device__ __forceinline__ unsigned int packh2(float a, float b) {
  const __half ha = __float2half(a), hb = __float2half(b);
  const unsigned short ua = *(const unsigned short*)&ha;
  const unsigned short ub = *(const unsigned short*)&hb;
  return (unsigned int)ua | ((unsigned int)ub << 16);
}
// select fp16 weight for this lane's head out of packed {y=h01, z=h23}
__device__ __forceinline__ float pickw(const int4 e, const int head) {
  const unsigned int d = (head & 2) ? (unsigned int)e.z : (unsigned int)e.y;
  const unsigned short us =
      (head & 1) ? (unsigned short)(d >> 16) : (unsigned short)(d & 0xffffu);
  const __half h = *(const __half*)&us;
  return __half2float(h);
}
// fma 8 bf16 features (one uint4) into acc[8] with scalar weight c
__device__ __forceinline__ void accum8(const uint4 g, const float c,
                                       float* acc) {
  float lo, hi;
  bf2x(g.x, lo, hi);
  acc[0] = fmaf(c, lo, acc[0]);
  acc[1] = fmaf(c, hi, acc[1]);
  bf2x(g.y, lo, hi);
  acc[2] = fmaf(c, lo, acc[2]);
  acc[3] = fmaf(c, hi, acc[3]);
  bf2x(g.z, lo, hi);
  acc[4] = fmaf(c, lo, acc[4]);
  acc[5] = fmaf(c, hi, acc[5]);
  bf2x(g.w, lo, hi);
  acc[6] = fmaf(c, lo, acc[6]);
  acc[7] = fmaf(c, hi, acc[7]);
}

// ---------------------------------------------------------------------------
// MFMA GEMM: C[M,128] = A[M,128] @ W[128,128]^T (+bias), W row-major [o][k].
// A input: fp32 (Af) or bf16 (Ab). Output: bf16 (Cb) or fp32+bias (Cf).
// Block = 64 rows x 128 cols, 4 waves; K=128 staged once to LDS (bf16).
// Optional fused epilogue (a_s!=null): per-head attention dots
//   a_s[n,h] = sum_d C[n,32h+d]*att_src[h,d]  (likewise a_d) computed from
// the fp32 accumulators via 16 FMA/row + shfl_xor(1,2,4,8) intra-quad tree.
// ---------------------------------------------------------------------------
#define LDA 136

__global__ __launch_bounds__(256) void gemm_mfma(
    const float* __restrict__ Af, const unsigned short* __restrict__ Ab,
    const float* __restrict__ W, const float* __restrict__ bias,
    unsigned short* __restrict__ Cb, float* __restrict__ Cf,
    const float* __restrict__ att_src, const float* __restrict__ att_dst,
    float* __restrict__ a_s, float* __restrict__ a_d, int M) {
  __shared__ unsigned short sA[64 * LDA];   // [m][k]
  __shared__ unsigned short sW[128 * LDA];  // [o][k] == B^T
  const int tid = threadIdx.x;
  const int m0 = blockIdx.x * 64;

  {
    const int r = tid >> 1;
    const int c0 = (tid & 1) * 64;
#pragma unroll
    for (int j = 0; j < 16; ++j) {
      const float4 v = *(const float4*)&W[r * 128 + c0 + j * 4];
      ushort4 u;
      u.x = f2bf(v.x);
      u.y = f2bf(v.y);
      u.z = f2bf(v.z);
      u.w = f2bf(v.w);
      *(ushort4*)&sW[r * LDA + c0 + j * 4] = u;
    }
  }
  {
    const int r = tid >> 2;
    const int gm = m0 + r;
    const int c0 = (tid & 3) * 32;
    if (gm < M) {
      if (Af) {
#pragma unroll
        for (int j = 0; j < 8; ++j) {
          const float4 v = *(const float4*)&Af[(size_t)gm * 128 + c0 + j * 4];
          ushort4 u;
          u.x = f2bf(v.x);
          u.y = f2bf(v.y);
          u.z = f2bf(v.z);
          u.w = f2bf(v.w);
          *(ushort4*)&sA[r * LDA + c0 + j * 4] = u;
        }
      } else {
#pragma unroll
        for (int j = 0; j < 4; ++j) {
          const uint4 v = *(const uint4*)&Ab[(size_t)gm * 128 + c0 + j * 8];
          *(uint4*)&sA[r * LDA + c0 + j * 8] = v;
        }
      }
    } else {
#pragma unroll
      for (int j = 0; j < 4; ++j) {
        uint4 z;
        z.x = z.y = z.z = z.w = 0u;
        *(uint4*)&sA[r * LDA + c0 + j * 8] = z;
      }
    }
  }
  __syncthreads();

  const int wv = tid >> 6;
  const int lane = tid & 63;
  const int l16 = lane & 15;
  const int quad = lane >> 4;

  floatx4 acc[8];
#pragma unroll
  for (int i = 0; i < 8; ++i) acc[i] = (floatx4){0.f, 0.f, 0.f, 0.f};

  const unsigned short* aRow = &sA[(wv * 16 + l16) * LDA + quad * 8];
#pragma unroll
  for (int kc = 0; kc < 4; ++kc) {
    const short8 afrag = *(const short8*)(aRow + kc * 32);
#pragma unroll
    for (int nt = 0; nt < 8; ++nt) {
      const short8 bfrag =
          *(const short8*)&sW[(nt * 16 + l16) * LDA + kc * 32 + quad * 8];
      acc[nt] =
          __builtin_amdgcn_mfma_f32_16x16x32_bf16(afrag, bfrag, acc[nt], 0, 0, 0);
    }
  }

  const int mrow = m0 + wv * 16 + quad * 4;
#pragma unroll
  for (int nt = 0; nt < 8; ++nt) {
    const int col = nt * 16 + l16;
    const float bv = Cf ? bias[col] : 0.f;
#pragma unroll
    for (int r = 0; r < 4; ++r) {
      const int gm = mrow + r;
      if (gm < M) {
        const float v = acc[nt][r];
        if (Cb)
          Cb[(size_t)gm * 128 + col] = f2bf(v);
        else
          Cf[(size_t)gm * 128 + col] = v + bv;
      }
    }
  }

  // fused attention-dot epilogue (gemm1 only)
  if (a_s) {
    float avs[8], avd[8];
#pragma unroll
    for (int nt = 0; nt < 8; ++nt) {
      avs[nt] = att_src[nt * 16 + l16];  // flat [h*32+d], col = nt*16+l16
      avd[nt] = att_dst[nt * 16 + l16];
    }
#pragma unroll
    for (int r = 0; r < 4; ++r) {
      float ps0 = acc[0][r] * avs[0] + acc[1][r] * avs[1];
      float ps1 = acc[2][r] * avs[2] + acc[3][r] * avs[3];
      float ps2 = acc[4][r] * avs[4] + acc[5][r] * avs[5];
      float ps3 = acc[6][r] * avs[6] + acc[7][r] * avs[7];
      float pd0 = acc[0][r] * avd[0] + acc[1][r] * avd[1];
      float pd1 = acc[2][r] * avd[2] + acc[3][r] * avd[3];
      float pd2 = acc[4][r] * avd[4] + acc[5][r] * avd[5];
      float pd3 = acc[6][r] * avd[6] + acc[7][r] * avd[7];
#pragma unroll
      for (int off = 1; off < 16; off <<= 1) {
        ps0 += __shfl_xor(ps0, off);
        ps1 += __shfl_xor(ps1, off);
        ps2 += __shfl_xor(ps2, off);
        ps3 += __shfl_xor(ps3, off);
        pd0 += __shfl_xor(pd0, off);
        pd1 += __shfl_xor(pd1, off);
        pd2 += __shfl_xor(pd2, off);
        pd3 += __shfl_xor(pd3, off);
      }
      const int gm = mrow + r;
      if (gm < M) {
        const int hs = l16 & 3;
        // compile-time-indexed select (avoid scratch), lanes 0-3 -> a_s,
        // lanes 4-7 -> a_d
        float vs = ps0;
        if (hs == 1) vs = ps1;
        if (hs == 2) vs = ps2;
        if (hs == 3) vs = ps3;
        float vd = pd0;
        if (hs == 1) vd = pd1;
        if (hs == 2) vd = pd2;
        if (hs == 3) vd = pd3;
        if (l16 < 4)
          a_s[gm * 4 + hs] = vs;
        else if (l16 < 8)
          a_d[gm * 4 + hs] = vd;
      }
    }
  }
}

// ---------------------------------------------------------------------------
// CSR build: histogram of dst, segment allocation via wave-scan + one atomic
// per wave, scatter (fused with per-edge softmax-weight precompute; emits
// 16 B records {src, fp16 w01, fp16 w23, 0}).
// ---------------------------------------------------------------------------
__global__ void hist_kernel(const int* __restrict__ dst, int* __restrict__ deg) {
  const int i = blockIdx.x * blockDim.x + threadIdx.x;
  if (i < EE) atomicAdd(&deg[dst[i]], 1);
}

__global__ __launch_bounds__(256) void alloc_kernel(const int* __restrict__ deg,
                                                    int* __restrict__ rowptr,
                                                    int* __restrict__ cur,
                                                    int* __restrict__ counter) {
  const int i = blockIdx.x * blockDim.x + threadIdx.x;
  const int lane = threadIdx.x & 63;
  const int d = (i < NN) ? deg[i] : 0;
  int s = d;
#pragma unroll
  for (int off = 1; off < 64; off <<= 1) {
    const int v = __shfl_up(s, off, 64);
    if (lane >= off) s += v;
  }
  const int total = __shfl(s, 63, 64);
  int base = 0;
  if (lane == 63) base = atomicAdd(counter, total);
  base = __shfl(base, 63, 64);
  const int p = base + s - d;
  if (i < NN) {
    rowptr[i] = p;
    cur[i] = p;
  }
}

__global__ void scatter_kernel(const int* __restrict__ src,
                               const int* __restrict__ dst,
                               const float* __restrict__ a_s,
                               const float* __restrict__ a_d,
                               int* __restrict__ cur, int4* __restrict__ ebuf) {
  const int i = blockIdx.x * blockDim.x + threadIdx.x;
  if (i >= EE) return;
  const int s = src[i];
  const int d = dst[i];
  const int p = atomicAdd(&cur[d], 1);
  const float4 as = *(const float4*)&a_s[s * 4];
  const float4 ad = *(const float4*)&a_d[d * 4];
  float4 l;
  l.x = as.x + ad.x;
  l.y = as.y + ad.y;
  l.z = as.z + ad.z;
  l.w = as.w + ad.w;
  l.x = l.x > 0.f ? l.x : NEG_SLOPE * l.x;
  l.y = l.y > 0.f ? l.y : NEG_SLOPE * l.y;
  l.z = l.z > 0.f ? l.z : NEG_SLOPE * l.z;
  l.w = l.w > 0.f ? l.w : NEG_SLOPE * l.w;
  int4 e;
  e.x = s;
  e.y = (int)packh2(__expf(l.x), __expf(l.y));
  e.z = (int)packh2(__expf(l.z), __expf(l.w));
  e.w = 0;
  ebuf[p] = e;
}

// ---------------------------------------------------------------------------
// Aggregate: one wave per destination node, quarter-wave per edge.
// Lane layout: q = lane>>4 (edge slot), f = lane&15 (feature group).
// Lane owns features [8f, 8f+8) -> one uint4 (16 B) of the bf16 feature row;
// its head is f>>2 (head-aligned). Per loop iteration the wave processes 4
// edges: one uint4 record load/lane (4 records = 64 B per quarter-group) +
// one uint4 feature gather. Records software-pipelined. Per-head denominator
// + features reduce across quarters via shfl_xor(16/32); quarter 0 stores.
// ---------------------------------------------------------------------------
__global__ __launch_bounds__(256) void aggregate_kernel(
    const uint4* __restrict__ hbd4, const float* __restrict__ a_s,
    const float* __restrict__ a_d, const float* __restrict__ bias_gat,
    const int* __restrict__ rowptr, const int* __restrict__ deg,
    const int4* __restrict__ ebuf, uint4* __restrict__ obd4) {
  const int wave = (blockIdx.x * blockDim.x + threadIdx.x) >> 6;
  if (wave >= NN) return;
  const int lane = threadIdx.x & 63;
  const int q = lane >> 4;
  const int f = lane & 15;
  const int head = f >> 2;
  const int n = wave;

  float acc[8];
  float ds;
  {  // self loop (only quarter 0 contributes; others start at zero)
    const float l0 = a_s[n * 4 + head] + a_d[n * 4 + head];
    const float l = fmaxf(l0, NEG_SLOPE * l0);
    float cs = __expf(l);
    if (q != 0) cs = 0.f;
    const uint4 g = hbd4[(size_t)n * 16 + f];
    float lo, hi;
    bf2x(g.x, lo, hi);
    acc[0] = cs * lo;
    acc[1] = cs * hi;
    bf2x(g.y, lo, hi);
    acc[2] = cs * lo;
    acc[3] = cs * hi;
    bf2x(g.z, lo, hi);
    acc[4] = cs * lo;
    acc[5] = cs * hi;
    bf2x(g.w, lo, hi);
    acc[6] = cs * lo;
    acc[7] = cs * hi;
    ds = cs;
  }

  const int beg = rowptr[n];
  const int end = beg + deg[n];
  if (beg < end) {
    int idx = beg + q;
    bool valid = idx < end;
    int4 e = ebuf[valid ? idx : end - 1];
    for (int i = beg; i < end; i += 4) {
      // gather current 4 edges' features (one uint4/lane)
      const uint4 g = hbd4[(size_t)e.x * 16 + f];
      // prefetch next records while the gather is in flight
      const int nidx = i + 4 + q;
      const bool nvalid = nidx < end;
      const int4 en = ebuf[nvalid ? nidx : end - 1];
      // weight for this lane's head (zero on masked tail slots)
      float c = pickw(e, head);
      if (!valid) c = 0.f;
      accum8(g, c, acc);
      ds += c;
      e = en;
      valid = nvalid;
    }
  }

  // reduce across the 4 quarters (lanes l, l^16, l^32, l^48 share f)
#pragma unroll
  for (int j = 0; j < 8; ++j) {
    acc[j] += __shfl_xor(acc[j], 16);
    acc[j] += __shfl_xor(acc[j], 32);
  }
  ds += __shfl_xor(ds, 16);
  ds += __shfl_xor(ds, 32);

  if (q == 0) {
    const float inv = 1.0f / ds;
    const float4 b0 = *(const float4*)&bias_gat[f * 8];
    const float4 b1 = *(const float4*)&bias_gat[f * 8 + 4];
    float v0 = acc[0] * inv + b0.x;
    float v1 = acc[1] * inv + b0.y;
    float v2 = acc[2] * inv + b0.z;
    float v3 = acc[3] * inv + b0.w;
    float v4 = acc[4] * inv + b1.x;
    float v5 = acc[5] * inv + b1.y;
    float v6 = acc[6] * inv + b1.z;
    float v7 = acc[7] * inv + b1.w;
    v0 = v0 > 0.f ? v0 : 0.f;
    v1 = v1 > 0.f ? v1 : 0.f;
    v2 = v2 > 0.f ? v2 : 0.f;
    v3 = v3 > 0.f ? v3 : 0.f;
    v4 = v4 > 0.f ? v4 : 0.f;
    v5 = v5 > 0.f ? v5 : 0.f;
    v6 = v6 > 0.f ? v6 : 0.f;
    v7 = v7 > 0.f ? v7 : 0.f;
    uint4 r;
    r.x = (unsigned int)f2bf(v0) | ((unsigned int)f2bf(v1) << 16);
    r.y = (unsigned int)f2bf(v2) | ((unsigned int)f2bf(v3) << 16);
    r.z = (unsigned int)f2bf(v4) | ((unsigned int)f2bf(v5) << 16);
    r.w = (unsigned int)f2bf(v6) | ((unsigned int)f2bf(v7) << 16);
    obd4[(size_t)n * 16 + f] = r;
  }
}

// ---------------------------------------------------------------------------
extern "C" void kernel_launch(void* const* d_in, const int* in_sizes, int n_in,
                              void* d_out, int out_size, void* d_ws,
                              size_t ws_size, hipStream_t stream) {
  const float* x = (const float*)d_in[0];
  const int* ei = (const int*)d_in[1];  // [2,E]: row0=src, row1=dst
  const float* W_gat = (const float*)d_in[2];
  const float* att_src = (const float*)d_in[3];
  const float* att_dst = (const float*)d_in[4];
  const float* bias_gat = (const float*)d_in[5];
  const float* W_lin = (const float*)d_in[6];
  const float* b_lin = (const float*)d_in[7];
  float* out = (float*)d_out;

  // workspace carve-up (16B aligned)
  char* ws = (char*)d_ws;
  size_t off = 0;
  unsigned short* hb = (unsigned short*)(ws + off);
  off += (size_t)NN * 128 * 2;  // 25.6 MB
  unsigned short* ob = (unsigned short*)(ws + off);
  off += (size_t)NN * 128 * 2;  // 25.6 MB
  float* a_s = (float*)(ws + off); off += (size_t)NN * 4 * 4;
  float* a_d = (float*)(ws + off); off += (size_t)NN * 4 * 4;
  int* deg = (int*)(ws + off); off += (size_t)NN * 4;
  int* rowptr = (int*)(ws + off); off += (size_t)(NN + 4) * 4;
  int* cur = (int*)(ws + off); off += (size_t)NN * 4;
  int* counter = (int*)(ws + off); off += 16;
  int4* ebuf = (int4*)(ws + off); off += (size_t)EE * 16;  // 25.6 MB

  const int* src = ei;
  const int* dst = ei + EE;

  // CSR histogram/alloc first (independent of gemm1)
  hipMemsetAsync(deg, 0, (size_t)NN * 4, stream);
  hipMemsetAsync(counter, 0, 16, stream);
  hist_kernel<<<(EE + 255) / 256, 256, 0, stream>>>(dst, deg);
  alloc_kernel<<<(NN + 255) / 256, 256, 0, stream>>>(deg, rowptr, cur, counter);
  // 1) hb = bf16(x @ W_gat^T) with fused a_s/a_d epilogue  [MFMA]
  gemm_mfma<<<(NN + 63) / 64, 256, 0, stream>>>(x, nullptr, W_gat, nullptr, hb,
                                                nullptr, att_src, att_dst, a_s,
                                                a_d, NN);
  // 2) scatter with fused edge-record precompute (16 B records)
  scatter_kernel<<<(EE + 255) / 256, 256, 0, stream>>>(src, dst, a_s, a_d, cur,
                                                       ebuf);
  // 3) softmax-weighted aggregation (+bias, relu) -> bf16
  aggregate_kernel<<<(NN + 3) / 4, 256, 0, stream>>>(
      (const uint4*)hb, a_s, a_d, bias_gat, rowptr, deg, ebuf,
      (uint4*)ob);
  // 4) out = ob @ W_lin^T + b_lin  [MFMA]
  gemm_mfma<<<(NN + 63) / 64, 256, 0, stream>>>(nullptr, ob, W_lin, b_lin,
                                                nullptr, out, nullptr, nullptr,
                                                nullptr, nullptr, NN);
}

// Round 4
// 389.355 us; speedup vs baseline: 1.1736x; 1.0605x over previous
//
#include <hip/hip_runtime.h>
#include <hip/hip_bf16.h>
#include <hip/hip_fp16.h>

// Problem constants (match reference)
#define NN 100000
#define EE 1600000
#define INF_DIM 128
#define NHEAD 4
#define HDIM 32
#define NEG_SLOPE 0.2f

typedef __attribute__((ext_vector_type(8))) short short8;
typedef __attribute__((ext_vector_type(4))) float floatx4;

__device__ __forceinline__ unsigned short f2bf(float x) {
  union { float f; unsigned int u; } c;
  c.f = x;
  const unsigned int r = c.u + 0x7fffu + ((c.u >> 16) & 1u);  // RNE
  return (unsigned short)(r >> 16);
}
// native packed fp32->bf16 convert (gfx950): D = {bf16(hi), bf16(lo)}
__device__ __forceinline__ unsigned int cvtpk_bf16(float lo, float hi) {
  unsigned int r;
  asm("v_cvt_pk_bf16_f32 %0, %1, %2" : "=v"(r) : "v"(lo), "v"(hi));
  return r;
}
__device__ __forceinline__ unsigned int packh2(float a, float b) {
  const __half ha = __float2half(a), hb = __float2half(b);
  const unsigned short ua = *(const unsigned short*)&ha;
  const unsigned short ub = *(const unsigned short*)&hb;
  return (unsigned int)ua | ((unsigned int)ub << 16);
}
// select fp16 weight for this lane's head out of packed {y=h01, z=h23}
__device__ __forceinline__ float pickw(const int4 e, const int head) {
  const unsigned int d = (head & 2) ? (unsigned int)e.z : (unsigned int)e.y;
  const unsigned short us =
      (head & 1) ? (unsigned short)(d >> 16) : (unsigned short)(d & 0xffffu);
  const __half h = *(const __half*)&us;
  return __half2float(h);
}
// fma 8 fp16 features (one uint4 = 4 half2) into acc[8] with scalar weight c
// (half2->float2 + fmaf fuses to v_fma_mix_f32)
__device__ __forceinline__ void accum8h(const uint4 g, const float c,
                                        float* acc) {
  union { uint4 u; __half2 h[4]; } v;
  v.u = g;
#pragma unroll
  for (int j = 0; j < 4; ++j) {
    const float2 f = __half22float2(v.h[j]);
    acc[2 * j] = fmaf(c, f.x, acc[2 * j]);
    acc[2 * j + 1] = fmaf(c, f.y, acc[2 * j + 1]);
  }
}

// ---------------------------------------------------------------------------
// MFMA GEMM: C[M,128] = A[M,128] @ W[128,128]^T (+bias), W16 bf16 row-major
// [o][k] (pre-converted). A input: fp32 (Af) or bf16 (Ab). Output: fp16 (Ch),
// or fp32+bias (Cf). Block = 64 rows x 128 cols, 4 waves; K=128 in LDS.
// Optional fused epilogue (a_s!=null): per-head attention dots from the fp32
// accumulators via 16 FMA/row + shfl_xor(1..8) intra-16 tree.
// ---------------------------------------------------------------------------
#define LDA 136

__global__ __launch_bounds__(256) void gemm_mfma(
    const float* __restrict__ Af, const unsigned short* __restrict__ Ab,
    const unsigned short* __restrict__ W16, const float* __restrict__ bias,
    unsigned short* __restrict__ Ch, float* __restrict__ Cf,
    const float* __restrict__ att_src, const float* __restrict__ att_dst,
    float* __restrict__ a_s, float* __restrict__ a_d, int M) {
  __shared__ unsigned short sA[64 * LDA];   // [m][k]
  __shared__ unsigned short sW[128 * LDA];  // [o][k] == B^T
  const int tid = threadIdx.x;
  const int m0 = blockIdx.x * 64;

  {  // W stage: pure bf16 copy, 64 shorts (8 x uint4) per thread
    const int r = tid >> 1;
    const int c0 = (tid & 1) * 64;
#pragma unroll
    for (int j = 0; j < 8; ++j) {
      *(uint4*)&sW[r * LDA + c0 + j * 8] =
          *(const uint4*)&W16[r * 128 + c0 + j * 8];
    }
  }
  {
    const int r = tid >> 2;
    const int gm = m0 + r;
    const int c0 = (tid & 3) * 32;
    if (gm < M) {
      if (Af) {
#pragma unroll
        for (int j = 0; j < 8; ++j) {
          const float4 v = *(const float4*)&Af[(size_t)gm * 128 + c0 + j * 4];
          uint2 u;
          u.x = cvtpk_bf16(v.x, v.y);
          u.y = cvtpk_bf16(v.z, v.w);
          *(uint2*)&sA[r * LDA + c0 + j * 4] = u;
        }
      } else {
#pragma unroll
        for (int j = 0; j < 4; ++j) {
          const uint4 v = *(const uint4*)&Ab[(size_t)gm * 128 + c0 + j * 8];
          *(uint4*)&sA[r * LDA + c0 + j * 8] = v;
        }
      }
    } else {
#pragma unroll
      for (int j = 0; j < 4; ++j) {
        uint4 z;
        z.x = z.y = z.z = z.w = 0u;
        *(uint4*)&sA[r * LDA + c0 + j * 8] = z;
      }
    }
  }
  __syncthreads();

  const int wv = tid >> 6;
  const int lane = tid & 63;
  const int l16 = lane & 15;
  const int quad = lane >> 4;

  floatx4 acc[8];
#pragma unroll
  for (int i = 0; i < 8; ++i) acc[i] = (floatx4){0.f, 0.f, 0.f, 0.f};

  const unsigned short* aRow = &sA[(wv * 16 + l16) * LDA + quad * 8];
#pragma unroll
  for (int kc = 0; kc < 4; ++kc) {
    const short8 afrag = *(const short8*)(aRow + kc * 32);
#pragma unroll
    for (int nt = 0; nt < 8; ++nt) {
      const short8 bfrag =
          *(const short8*)&sW[(nt * 16 + l16) * LDA + kc * 32 + quad * 8];
      acc[nt] =
          __builtin_amdgcn_mfma_f32_16x16x32_bf16(afrag, bfrag, acc[nt], 0, 0, 0);
    }
  }

  const int mrow = m0 + wv * 16 + quad * 4;
#pragma unroll
  for (int nt = 0; nt < 8; ++nt) {
    const int col = nt * 16 + l16;
    const float bv = Cf ? bias[col] : 0.f;
#pragma unroll
    for (int r = 0; r < 4; ++r) {
      const int gm = mrow + r;
      if (gm < M) {
        const float v = acc[nt][r];
        if (Ch) {
          const __half hh = __float2half(v);
          Ch[(size_t)gm * 128 + col] = *(const unsigned short*)&hh;
        } else {
          Cf[(size_t)gm * 128 + col] = v + bv;
        }
      }
    }
  }

  // fused attention-dot epilogue (gemm1 only)
  if (a_s) {
    float avs[8], avd[8];
#pragma unroll
    for (int nt = 0; nt < 8; ++nt) {
      avs[nt] = att_src[nt * 16 + l16];  // flat [h*32+d], col = nt*16+l16
      avd[nt] = att_dst[nt * 16 + l16];
    }
#pragma unroll
    for (int r = 0; r < 4; ++r) {
      float ps0 = acc[0][r] * avs[0] + acc[1][r] * avs[1];
      float ps1 = acc[2][r] * avs[2] + acc[3][r] * avs[3];
      float ps2 = acc[4][r] * avs[4] + acc[5][r] * avs[5];
      float ps3 = acc[6][r] * avs[6] + acc[7][r] * avs[7];
      float pd0 = acc[0][r] * avd[0] + acc[1][r] * avd[1];
      float pd1 = acc[2][r] * avd[2] + acc[3][r] * avd[3];
      float pd2 = acc[4][r] * avd[4] + acc[5][r] * avd[5];
      float pd3 = acc[6][r] * avd[6] + acc[7][r] * avd[7];
#pragma unroll
      for (int off = 1; off < 16; off <<= 1) {
        ps0 += __shfl_xor(ps0, off);
        ps1 += __shfl_xor(ps1, off);
        ps2 += __shfl_xor(ps2, off);
        ps3 += __shfl_xor(ps3, off);
        pd0 += __shfl_xor(pd0, off);
        pd1 += __shfl_xor(pd1, off);
        pd2 += __shfl_xor(pd2, off);
        pd3 += __shfl_xor(pd3, off);
      }
      const int gm = mrow + r;
      if (gm < M) {
        const int hs = l16 & 3;
        float vs = ps0;
        if (hs == 1) vs = ps1;
        if (hs == 2) vs = ps2;
        if (hs == 3) vs = ps3;
        float vd = pd0;
        if (hs == 1) vd = pd1;
        if (hs == 2) vd = pd2;
        if (hs == 3) vd = pd3;
        if (l16 < 4)
          a_s[gm * 4 + hs] = vs;
        else if (l16 < 8)
          a_d[gm * 4 + hs] = vd;
      }
    }
  }
}

// ---------------------------------------------------------------------------
// hist + one-shot fp32->bf16 weight conversion (first 8192 threads convert
// W_gat and W_lin, 4 elements each; the rest is the dst histogram).
// ---------------------------------------------------------------------------
__global__ void hist_kernel(const int* __restrict__ dst, int* __restrict__ deg,
                            const float* __restrict__ Wg,
                            const float* __restrict__ Wl,
                            unsigned short* __restrict__ Wg16,
                            unsigned short* __restrict__ Wl16) {
  const int i = blockIdx.x * blockDim.x + threadIdx.x;
  if (i < 8192) {  // 2 matrices x 4096 float4
    const int m = i >> 12;
    const int j = i & 4095;
    const float4 v = m ? ((const float4*)Wl)[j] : ((const float4*)Wg)[j];
    ushort4 u;
    u.x = f2bf(v.x);
    u.y = f2bf(v.y);
    u.z = f2bf(v.z);
    u.w = f2bf(v.w);
    if (m)
      ((ushort4*)Wl16)[j] = u;
    else
      ((ushort4*)Wg16)[j] = u;
  }
  if (i < EE) atomicAdd(&deg[dst[i]], 1);
}

__global__ __launch_bounds__(256) void alloc_kernel(const int* __restrict__ deg,
                                                    int* __restrict__ rowptr,
                                                    int* __restrict__ cur,
                                                    int* __restrict__ counter) {
  const int i = blockIdx.x * blockDim.x + threadIdx.x;
  const int lane = threadIdx.x & 63;
  const int d = (i < NN) ? deg[i] : 0;
  int s = d;
#pragma unroll
  for (int off = 1; off < 64; off <<= 1) {
    const int v = __shfl_up(s, off, 64);
    if (lane >= off) s += v;
  }
  const int total = __shfl(s, 63, 64);
  int base = 0;
  if (lane == 63) base = atomicAdd(counter, total);
  base = __shfl(base, 63, 64);
  const int p = base + s - d;
  if (i < NN) {
    rowptr[i] = p;
    cur[i] = p;
  }
}

// ---------------------------------------------------------------------------
// Scatter: 2 edges per thread (i, i+E/2) for 2x memory-level parallelism.
// Emits 16 B records {src, fp16 w01, fp16 w23, 0} at CSR positions.
// ---------------------------------------------------------------------------
__global__ void scatter_kernel(const int* __restrict__ src,
                               const int* __restrict__ dst,
                               const float* __restrict__ a_s,
                               const float* __restrict__ a_d,
                               int* __restrict__ cur, int4* __restrict__ ebuf) {
  const int iA = blockIdx.x * blockDim.x + threadIdx.x;
  const int iB = iA + (EE / 2);
  const int sA_ = src[iA];
  const int dA = dst[iA];
  const int sB_ = src[iB];
  const int dB = dst[iB];
  const int pA = atomicAdd(&cur[dA], 1);
  const int pB = atomicAdd(&cur[dB], 1);
  const float4 asA = *(const float4*)&a_s[sA_ * 4];
  const float4 adA = *(const float4*)&a_d[dA * 4];
  const float4 asB = *(const float4*)&a_s[sB_ * 4];
  const float4 adB = *(const float4*)&a_d[dB * 4];
  float4 lA, lB;
  lA.x = asA.x + adA.x;
  lA.y = asA.y + adA.y;
  lA.z = asA.z + adA.z;
  lA.w = asA.w + adA.w;
  lB.x = asB.x + adB.x;
  lB.y = asB.y + adB.y;
  lB.z = asB.z + adB.z;
  lB.w = asB.w + adB.w;
  lA.x = lA.x > 0.f ? lA.x : NEG_SLOPE * lA.x;
  lA.y = lA.y > 0.f ? lA.y : NEG_SLOPE * lA.y;
  lA.z = lA.z > 0.f ? lA.z : NEG_SLOPE * lA.z;
  lA.w = lA.w > 0.f ? lA.w : NEG_SLOPE * lA.w;
  lB.x = lB.x > 0.f ? lB.x : NEG_SLOPE * lB.x;
  lB.y = lB.y > 0.f ? lB.y : NEG_SLOPE * lB.y;
  lB.z = lB.z > 0.f ? lB.z : NEG_SLOPE * lB.z;
  lB.w = lB.w > 0.f ? lB.w : NEG_SLOPE * lB.w;
  int4 eA, eB;
  eA.x = sA_;
  eA.y = (int)packh2(__expf(lA.x), __expf(lA.y));
  eA.z = (int)packh2(__expf(lA.z), __expf(lA.w));
  eA.w = 0;
  eB.x = sB_;
  eB.y = (int)packh2(__expf(lB.x), __expf(lB.y));
  eB.z = (int)packh2(__expf(lB.z), __expf(lB.w));
  eB.w = 0;
  ebuf[pA] = eA;
  ebuf[pB] = eB;
}

// ---------------------------------------------------------------------------
// Aggregate: one wave per destination node, quarter-wave per edge.
// q = lane>>4 (edge slot), f = lane&15 (feature group, head = f>>2).
// 16-edge super-iteration: 4 record loads then 4 independent uint4 feature
// gathers in flight (statically unrolled), then consume. Features are fp16
// (v_fma_mix accumulate into fp32). Cross-quarter reduce via shfl_xor(16/32).
// ---------------------------------------------------------------------------
__global__ __launch_bounds__(256) void aggregate_kernel(
    const uint4* __restrict__ hbd4, const float* __restrict__ a_s,
    const float* __restrict__ a_d, const float* __restrict__ bias_gat,
    const int* __restrict__ rowptr, const int* __restrict__ deg,
    const int4* __restrict__ ebuf, uint4* __restrict__ obd4) {
  const int wave = (blockIdx.x * blockDim.x + threadIdx.x) >> 6;
  if (wave >= NN) return;
  const int lane = threadIdx.x & 63;
  const int q = lane >> 4;
  const int f = lane & 15;
  const int head = f >> 2;
  const int n = wave;

  float acc[8];
  float ds;
  {  // self loop (only quarter 0 contributes; others start at zero)
    const float l0 = a_s[n * 4 + head] + a_d[n * 4 + head];
    const float l = fmaxf(l0, NEG_SLOPE * l0);
    float cs = __expf(l);
    if (q != 0) cs = 0.f;
    union { uint4 u; __half2 h[4]; } v;
    v.u = hbd4[(size_t)n * 16 + f];
#pragma unroll
    for (int j = 0; j < 4; ++j) {
      const float2 fv = __half22float2(v.h[j]);
      acc[2 * j] = cs * fv.x;
      acc[2 * j + 1] = cs * fv.y;
    }
    ds = cs;
  }

  const int beg = rowptr[n];
  const int end = beg + deg[n];
  for (int i = beg; i < end; i += 16) {
    int4 e0, e1, e2, e3;
    {
      const int i0 = i + q, i1 = i + 4 + q, i2 = i + 8 + q, i3 = i + 12 + q;
      e0 = ebuf[i0 < end ? i0 : end - 1];
      e1 = ebuf[i1 < end ? i1 : end - 1];
      e2 = ebuf[i2 < end ? i2 : end - 1];
      e3 = ebuf[i3 < end ? i3 : end - 1];
    }
    // 4 independent feature gathers in flight
    const uint4 g0 = hbd4[(size_t)e0.x * 16 + f];
    const uint4 g1 = hbd4[(size_t)e1.x * 16 + f];
    const uint4 g2 = hbd4[(size_t)e2.x * 16 + f];
    const uint4 g3 = hbd4[(size_t)e3.x * 16 + f];
    float c0 = pickw(e0, head);
    float c1 = pickw(e1, head);
    float c2 = pickw(e2, head);
    float c3 = pickw(e3, head);
    if (i + q >= end) c0 = 0.f;
    if (i + 4 + q >= end) c1 = 0.f;
    if (i + 8 + q >= end) c2 = 0.f;
    if (i + 12 + q >= end) c3 = 0.f;
    accum8h(g0, c0, acc);
    accum8h(g1, c1, acc);
    accum8h(g2, c2, acc);
    accum8h(g3, c3, acc);
    ds += c0 + c1 + c2 + c3;
  }

  // reduce across the 4 quarters (lanes l, l^16, l^32, l^48 share f)
#pragma unroll
  for (int j = 0; j < 8; ++j) {
    acc[j] += __shfl_xor(acc[j], 16);
    acc[j] += __shfl_xor(acc[j], 32);
  }
  ds += __shfl_xor(ds, 16);
  ds += __shfl_xor(ds, 32);

  if (q == 0) {
    const float inv = 1.0f / ds;
    const float4 b0 = *(const float4*)&bias_gat[f * 8];
    const float4 b1 = *(const float4*)&bias_gat[f * 8 + 4];
    float v0 = acc[0] * inv + b0.x;
    float v1 = acc[1] * inv + b0.y;
    float v2 = acc[2] * inv + b0.z;
    float v3 = acc[3] * inv + b0.w;
    float v4 = acc[4] * inv + b1.x;
    float v5 = acc[5] * inv + b1.y;
    float v6 = acc[6] * inv + b1.z;
    float v7 = acc[7] * inv + b1.w;
    v0 = v0 > 0.f ? v0 : 0.f;
    v1 = v1 > 0.f ? v1 : 0.f;
    v2 = v2 > 0.f ? v2 : 0.f;
    v3 = v3 > 0.f ? v3 : 0.f;
    v4 = v4 > 0.f ? v4 : 0.f;
    v5 = v5 > 0.f ? v5 : 0.f;
    v6 = v6 > 0.f ? v6 : 0.f;
    v7 = v7 > 0.f ? v7 : 0.f;
    uint4 r;
    r.x = (unsigned int)f2bf(v0) | ((unsigned int)f2bf(v1) << 16);
    r.y = (unsigned int)f2bf(v2) | ((unsigned int)f2bf(v3) << 16);
    r.z = (unsigned int)f2bf(v4) | ((unsigned int)f2bf(v5) << 16);
    r.w = (unsigned int)f2bf(v6) | ((unsigned int)f2bf(v7) << 16);
    obd4[(size_t)n * 16 + f] = r;
  }
}

// ---------------------------------------------------------------------------
extern "C" void kernel_launch(void* const* d_in, const int* in_sizes, int n_in,
                              void* d_out, int out_size, void* d_ws,
                              size_t ws_size, hipStream_t stream) {
  const float* x = (const float*)d_in[0];
  const int* ei = (const int*)d_in[1];  // [2,E]: row0=src, row1=dst
  const float* W_gat = (const float*)d_in[2];
  const float* att_src = (const float*)d_in[3];
  const float* att_dst = (const float*)d_in[4];
  const float* bias_gat = (const float*)d_in[5];
  const float* W_lin = (const float*)d_in[6];
  const float* b_lin = (const float*)d_in[7];
  float* out = (float*)d_out;

  // workspace carve-up (16B aligned)
  char* ws = (char*)d_ws;
  size_t off = 0;
  unsigned short* hb = (unsigned short*)(ws + off);
  off += (size_t)NN * 128 * 2;  // 25.6 MB (fp16 features)
  unsigned short* ob = (unsigned short*)(ws + off);
  off += (size_t)NN * 128 * 2;  // 25.6 MB (bf16 aggregate out)
  float* a_s = (float*)(ws + off); off += (size_t)NN * 4 * 4;
  float* a_d = (float*)(ws + off); off += (size_t)NN * 4 * 4;
  int* deg = (int*)(ws + off); off += (size_t)NN * 4;
  int* rowptr = (int*)(ws + off); off += (size_t)(NN + 4) * 4;
  int* cur = (int*)(ws + off); off += (size_t)NN * 4;
  int* counter = (int*)(ws + off); off += 16;
  unsigned short* Wg16 = (unsigned short*)(ws + off); off += 128 * 128 * 2;
  unsigned short* Wl16 = (unsigned short*)(ws + off); off += 128 * 128 * 2;
  int4* ebuf = (int4*)(ws + off); off += (size_t)EE * 16;  // 25.6 MB

  const int* src = ei;
  const int* dst = ei + EE;

  // CSR histogram + weight bf16 pre-convert (independent of gemm1)
  hipMemsetAsync(deg, 0, (size_t)NN * 4, stream);
  hipMemsetAsync(counter, 0, 16, stream);
  hist_kernel<<<(EE + 255) / 256, 256, 0, stream>>>(dst, deg, W_gat, W_lin,
                                                    Wg16, Wl16);
  alloc_kernel<<<(NN + 255) / 256, 256, 0, stream>>>(deg, rowptr, cur, counter);
  // 1) hb = fp16(x @ W_gat^T) with fused a_s/a_d epilogue  [MFMA]
  gemm_mfma<<<(NN + 63) / 64, 256, 0, stream>>>(x, nullptr, Wg16, nullptr, hb,
                                                nullptr, att_src, att_dst, a_s,
                                                a_d, NN);
  // 2) scatter with fused edge-record precompute (16 B records, 2 edges/thr)
  scatter_kernel<<<(EE / 2 + 255) / 256, 256, 0, stream>>>(src, dst, a_s, a_d,
                                                           cur, ebuf);
  // 3) softmax-weighted aggregation (+bias, relu) -> bf16
  aggregate_kernel<<<(NN + 3) / 4, 256, 0, stream>>>(
      (const uint4*)hb, a_s, a_d, bias_gat, rowptr, deg, ebuf,
      (uint4*)ob);
  // 4) out = ob @ W_lin^T + b_lin  [MFMA]
  gemm_mfma<<<(NN + 63) / 64, 256, 0, stream>>>(nullptr, ob, Wl16, b_lin,
                                                nullptr, out, nullptr, nullptr,
                                                nullptr, nullptr, NN);
}